// Round 1
// baseline (120.346 us; speedup 1.0000x reference)
//
#include <hip/hip_runtime.h>

#define NB 4096
#define NSTEPS 4
#define E 128
#define OUT_DIM 16

__global__ __launch_bounds__(128) void modulenet_fused(
    const int* __restrict__ author_ids,
    const int* __restrict__ module_ids,
    const float* __restrict__ embed,
    const float* __restrict__ W,
    const float* __restrict__ bias,
    const float* __restrict__ cls_W,
    const float* __restrict__ cls_b,
    float* __restrict__ out)
{
    __shared__ float xs[E];
    const int b = blockIdx.x;
    const int t = threadIdx.x;

    // gather embedding row (coalesced 512B per block)
    const int aid = author_ids[b];
    xs[t] = embed[(size_t)aid * E + t];
    __syncthreads();

    // 4 dependent matvecs; thread t owns output row t
    for (int s = 0; s < NSTEPS; ++s) {
        const int m = module_ids[b * NSTEPS + s];
        const float4* __restrict__ wrow =
            (const float4*)(W + ((size_t)m * E + t) * E);
        const float4* __restrict__ xv = (const float4*)xs;
        float acc = bias[m * E + t];
        #pragma unroll 8
        for (int i = 0; i < E / 4; ++i) {
            float4 w = wrow[i];
            float4 x4 = xv[i];     // LDS broadcast (same addr all lanes)
            acc += w.x * x4.x + w.y * x4.y + w.z * x4.z + w.w * x4.w;
        }
        float val = (s < NSTEPS - 1) ? tanhf(acc) : acc;
        __syncthreads();           // everyone done reading xs
        xs[t] = val;
        __syncthreads();           // new x visible
    }

    // classifier: 8 threads per output j, 16 elems each, shuffle-reduce
    const int j = t >> 3;          // 0..15
    const int part = t & 7;        // 0..7
    const float4* __restrict__ cw = (const float4*)(cls_W + j * E + part * 16);
    const float4* __restrict__ xv = (const float4*)(xs + part * 16);
    float acc = 0.f;
    #pragma unroll
    for (int i = 0; i < 4; ++i) {
        float4 w = cw[i];
        float4 x4 = xv[i];
        acc += w.x * x4.x + w.y * x4.y + w.z * x4.z + w.w * x4.w;
    }
    acc += __shfl_down(acc, 4, 8);
    acc += __shfl_down(acc, 2, 8);
    acc += __shfl_down(acc, 1, 8);
    if (part == 0) out[b * OUT_DIM + j] = acc + cls_b[j];
}

extern "C" void kernel_launch(void* const* d_in, const int* in_sizes, int n_in,
                              void* d_out, int out_size, void* d_ws, size_t ws_size,
                              hipStream_t stream) {
    const int*   author_ids = (const int*)d_in[0];
    const int*   module_ids = (const int*)d_in[1];
    const float* embed      = (const float*)d_in[2];
    const float* W          = (const float*)d_in[3];
    const float* bias       = (const float*)d_in[4];
    const float* cls_W      = (const float*)d_in[5];
    const float* cls_b      = (const float*)d_in[6];
    float* out = (float*)d_out;

    modulenet_fused<<<NB, 128, 0, stream>>>(
        author_ids, module_ids, embed, W, bias, cls_W, cls_b, out);
}

// Round 2
// 71.546 us; speedup vs baseline: 1.6821x; 1.6821x over previous
//
#include <hip/hip_runtime.h>

#define B_TOT   4096
#define NSTEPS  4
#define E       128
#define OUT_DIM 16
#define NMOD    64
#define KSPLIT  8
#define TILE    16

// ws layout:
//   int  cnt [4][64]      at int-offset 0
//   int  off [4][64]      at int-offset 256
//   int  perm[4][4096]    at int-offset 512
//   float xbuf[4096][128] at byte-offset (512+16384)*4 = 67584 (16B aligned)

__global__ __launch_bounds__(1024) void sort_kernel(const int* __restrict__ mids,
                                                    int* __restrict__ ws)
{
    const int s = blockIdx.x;       // step
    const int t = threadIdx.x;
    __shared__ int h[NMOD];
    __shared__ int o[NMOD];
    if (t < NMOD) h[t] = 0;
    __syncthreads();
    for (int b = t; b < B_TOT; b += 1024)
        atomicAdd(&h[mids[b * NSTEPS + s]], 1);
    __syncthreads();
    if (t == 0) {
        int run = 0;
        for (int m = 0; m < NMOD; ++m) { o[m] = run; run += h[m]; }
    }
    __syncthreads();
    if (t < NMOD) {
        ws[s * NMOD + t]       = h[t];   // cnt
        ws[256 + s * NMOD + t] = o[t];   // off
        h[t] = o[t];                     // reuse as cursor
    }
    __syncthreads();
    int* perm = ws + 512 + s * B_TOT;
    for (int b = t; b < B_TOT; b += 1024) {
        const int m = mids[b * NSTEPS + s];
        const int p = atomicAdd(&h[m], 1);
        perm[p] = b;
    }
}

template <bool FIRST, bool LAST>
__global__ __launch_bounds__(256) void step_kernel(
    const int s,
    const int* __restrict__ ws,
    const int* __restrict__ author_ids,
    const float* __restrict__ embed,
    const float* __restrict__ W,
    const float* __restrict__ bias,
    const float* __restrict__ cls_W,
    const float* __restrict__ cls_b,
    float* __restrict__ xbuf,
    float* __restrict__ out)
{
    const int m = blockIdx.x / KSPLIT;
    const int k = blockIdx.x % KSPLIT;
    const int cnt = ws[s * NMOD + m];
    const int off = ws[256 + s * NMOD + m];
    const int lo = off + (cnt * k) / KSPLIT;
    const int hi = off + (cnt * (k + 1)) / KSPLIT;
    if (lo >= hi) return;   // uniform across block: no syncthreads yet

    const int t = threadIdx.x;

    __shared__ __align__(16) float Wl[E][E + 4];   // stride 132 floats = 528 B
    __shared__ __align__(16) float Xl[TILE][E];
    __shared__ __align__(16) float bl[E];
    __shared__ int rowb[TILE];

    // ---- stage W[m] (64 KB) and bias into LDS ----
    {
        const float4* __restrict__ wg = (const float4*)(W + (size_t)m * E * E);
        #pragma unroll
        for (int i = 0; i < 16; ++i) {
            const int c4 = i * 256 + t;            // float4 index 0..4095
            const float4 v = wg[c4];
            *(float4*)&Wl[c4 >> 5][(c4 & 31) * 4] = v;
        }
        if (t < 32) {
            const float4 v = ((const float4*)(bias + m * E))[t];
            *(float4*)&bl[t * 4] = v;
        }
    }

    const int* __restrict__ perm = ws + 512 + s * B_TOT;

    for (int base = lo; base < hi; base += TILE) {
        const int nb = min(TILE, hi - base);

        // ---- stage up to 16 x-rows (16 threads per row, 32B each) ----
        {
            const int i = t >> 4, q = t & 15;
            if (i < nb) {
                const int b = perm[base + i];
                if (q == 0) rowb[i] = b;
                const float* __restrict__ src =
                    FIRST ? (embed + (size_t)author_ids[b] * E)
                          : (xbuf + (size_t)b * E);
                const float4 v0 = ((const float4*)src)[2 * q];
                const float4 v1 = ((const float4*)src)[2 * q + 1];
                *(float4*)&Xl[i][q * 8]     = v0;
                *(float4*)&Xl[i][q * 8 + 4] = v1;
            } else {
                const float4 z = {0.f, 0.f, 0.f, 0.f};
                *(float4*)&Xl[i][q * 8]     = z;
                *(float4*)&Xl[i][q * 8 + 4] = z;
            }
        }
        __syncthreads();   // first iteration also covers W/bias staging

        // ---- 16x128 @ 128x128^T : thread (col cc, row-group rg) ----
        const int cc = t & 127;
        const int rg = t >> 7;
        float acc[8] = {0, 0, 0, 0, 0, 0, 0, 0};
        #pragma unroll 4
        for (int j = 0; j < 32; ++j) {
            const float4 w4 = *(const float4*)&Wl[cc][j * 4];
            #pragma unroll
            for (int r = 0; r < 8; ++r) {
                const float4 x4 = *(const float4*)&Xl[rg * 8 + r][j * 4]; // wave-uniform broadcast
                acc[r] += w4.x * x4.x + w4.y * x4.y + w4.z * x4.z + w4.w * x4.w;
            }
        }
        const float bb = bl[cc];

        if (!LAST) {
            #pragma unroll
            for (int r = 0; r < 8; ++r) {
                const int row = rg * 8 + r;
                if (row < nb)
                    xbuf[(size_t)rowb[row] * E + cc] = tanhf(acc[r] + bb);
            }
            __syncthreads();   // X readers done before next subtile overwrites
        } else {
            __syncthreads();   // all X reads done
            #pragma unroll
            for (int r = 0; r < 8; ++r)
                Xl[rg * 8 + r][cc] = acc[r] + bb;   // y into Xl
            __syncthreads();
            // ---- fused classifier: thread (row, j) ----
            const int row = t >> 4;
            const int j = t & 15;
            if (row < nb) {
                const float4* __restrict__ cw = (const float4*)(cls_W + j * E);
                float a2 = 0.f;
                #pragma unroll 8
                for (int jj = 0; jj < 32; ++jj) {
                    const float4 y4 = *(const float4*)&Xl[row][jj * 4];  // 16-lane broadcast
                    const float4 w4 = cw[jj];                            // L1-resident, 8 KB
                    a2 += y4.x * w4.x + y4.y * w4.y + y4.z * w4.z + y4.w * w4.w;
                }
                out[(size_t)rowb[row] * OUT_DIM + j] = a2 + cls_b[j];
            }
            __syncthreads();
        }
    }
}

extern "C" void kernel_launch(void* const* d_in, const int* in_sizes, int n_in,
                              void* d_out, int out_size, void* d_ws, size_t ws_size,
                              hipStream_t stream) {
    const int*   author_ids = (const int*)d_in[0];
    const int*   module_ids = (const int*)d_in[1];
    const float* embed      = (const float*)d_in[2];
    const float* W          = (const float*)d_in[3];
    const float* bias       = (const float*)d_in[4];
    const float* cls_W      = (const float*)d_in[5];
    const float* cls_b      = (const float*)d_in[6];
    float* out = (float*)d_out;

    int*   wsI  = (int*)d_ws;
    float* xbuf = (float*)((char*)d_ws + (512 + NSTEPS * B_TOT) * sizeof(int));

    sort_kernel<<<NSTEPS, 1024, 0, stream>>>(module_ids, wsI);

    const dim3 g(NMOD * KSPLIT), blk(256);
    step_kernel<true,  false><<<g, blk, 0, stream>>>(0, wsI, author_ids, embed, W, bias, cls_W, cls_b, xbuf, out);
    step_kernel<false, false><<<g, blk, 0, stream>>>(1, wsI, author_ids, embed, W, bias, cls_W, cls_b, xbuf, out);
    step_kernel<false, false><<<g, blk, 0, stream>>>(2, wsI, author_ids, embed, W, bias, cls_W, cls_b, xbuf, out);
    step_kernel<false, true ><<<g, blk, 0, stream>>>(3, wsI, author_ids, embed, W, bias, cls_W, cls_b, xbuf, out);
}